// Round 3
// baseline (129.901 us; speedup 1.0000x reference)
//
#include <hip/hip_runtime.h>
#include <math.h>

// RotatedIoULoss: per-pair rotated-box IoU loss, mean-reduced to one f32 scalar.
// Inputs: d_in[0]=pred (n,5) f32, d_in[1]=target (n,5) f32, d_in[2]=weight (n,) f32.
// Output: d_out[0] = mean(-log(max(iou,1e-6)) * weight).
//
// R1: branchless Green's-theorem intersection (generic halfplane Liang-Barsky).
// R2: 4 boxes/thread, float4 loads, 4 independent pipelines for ILP.
// R3: rectangle structure — AABB slab clip per edge; closed-form translation
//     correction. ~310 VALU-equiv/box.
// R4 (FAILED +11us), R5 (FAILED +23us): occupancy theories. R5's counters
//     (VGPR=36, VALUBusy=14%, hbm~0 steady) showed the real limiter: 11
//     scalar stride-20B loads/thread fragment into ~dozens of TA/L1
//     transactions per wave64 instruction -> vector-memory transaction-rate
//     bound, VALU idle. R3 was coalesced but TLP-starved; R5 TLP-rich but
//     uncoalesced.
// R6: both axes at once — LDS staging. Block stages its 256-box slab of
//     pred/target with fully-coalesced float4 loads (1KiB/wave/instr), then
//     threads read 5+5 floats from LDS (5*tid+j: lanes t,t+32 share a bank,
//     2-way alias = free). weight stays a direct coalesced global load.
//     1 box/thread; VGPR target <=64 -> 8 waves/SIMD eligible.

__device__ __forceinline__ float rcpf(float x) { return __builtin_amdgcn_rcpf(x); }

template <bool TRACK>
__device__ __forceinline__ void clip_edge(float u0, float v0, float dx, float dy,
                                          float rx, float ry, float hw, float hh,
                                          float& S, float& Dx, float& Dy)
{
    float ta = (-hw - u0) * rx;
    float tb = ( hw - u0) * rx;
    float tc = (-hh - v0) * ry;
    float td = ( hh - v0) * ry;
    float tumin = fminf(ta, tb), tumax = fmaxf(ta, tb);
    float tvmin = fminf(tc, td), tvmax = fmaxf(tc, td);
    float t0 = fmaxf(fmaxf(tumin, tvmin), 0.0f);   // v_max3
    float t1 = fminf(fminf(tumax, tvmax), 1.0f);   // v_min3
    bool valid = t1 > t0;
    float sx = fmaf(t0, dx, u0), sy = fmaf(t0, dy, v0);
    float ex = fmaf(t1, dx, u0), ey = fmaf(t1, dy, v0);
    float c = sx * ey - sy * ex;
    S += valid ? c : 0.0f;
    if (TRACK) {
        Dx += valid ? (ex - sx) : 0.0f;
        Dy += valid ? (ey - sy) : 0.0f;
    }
}

// Quad with CCW corners (+U+V, -U+V, -U-V, +U-V) + c, clipped to AABB(hw,hh).
// Edge vectors are (-2U, -2V, +2U, +2V) -> only 4 distinct rcps.
template <bool TRACK>
__device__ __forceinline__ float clip_quad(float Ux, float Uy, float Vx, float Vy,
                                           float cx, float cy, float hw, float hh,
                                           float& Dx, float& Dy)
{
    float d0x = -2.0f * Ux, d0y = -2.0f * Uy;   // edge 0 and (negated) edge 2
    float d1x = -2.0f * Vx, d1y = -2.0f * Vy;   // edge 1 and (negated) edge 3
    float r0x = rcpf(d0x), r0y = rcpf(d0y);
    float r1x = rcpf(d1x), r1y = rcpf(d1y);

    float sxv = Ux + Vx, syv = Uy + Vy;   // c0 offset
    float dxv = Ux - Vx, dyv = Uy - Vy;   // c3 offset

    float S = 0.0f;
    clip_edge<TRACK>( sxv + cx,  syv + cy,  d0x,  d0y,  r0x,  r0y, hw, hh, S, Dx, Dy);
    clip_edge<TRACK>(-dxv + cx, -dyv + cy,  d1x,  d1y,  r1x,  r1y, hw, hh, S, Dx, Dy);
    clip_edge<TRACK>(-sxv + cx, -syv + cy, -d0x, -d0y, -r0x, -r0y, hw, hh, S, Dx, Dy);
    clip_edge<TRACK>( dxv + cx,  dyv + cy, -d1x, -d1y, -r1x, -r1y, hw, hh, S, Dx, Dy);
    return S;
}

__device__ __forceinline__ float riou_one(float px, float py, float pw, float ph, float pa,
                                          float qx, float qy, float qw, float qh, float qa,
                                          float w)
{
    float hw1 = 0.5f * pw, hh1 = 0.5f * ph;
    float hw2 = 0.5f * qw, hh2 = 0.5f * qh;

    float ca = __cosf(pa), sa = __sinf(pa);
    float delta = pa - qa;
    float cr = __cosf(delta), sr = __sinf(delta);

    float ox = qx - px, oy = qy - py;          // q - p in world frame
    // Q center in P-frame: R(-pa) * o
    float cPx =  ca * ox + sa * oy;
    float cPy = -sa * ox + ca * oy;
    // P center in Q-frame: cQ = -R_PQ * cP, R_PQ = [cr -sr; sr cr]
    float cQx = -(cr * cPx - sr * cPy);
    float cQy = -(sr * cPx + cr * cPy);

    // Set A: P's quad in Q-frame, clip box (hw2,hh2).
    float dum0 = 0.0f, dum1 = 0.0f;
    float SA = clip_quad<false>(cr * hw1, sr * hw1, -sr * hh1, cr * hh1,
                                cQx, cQy, hw2, hh2, dum0, dum1);

    // Set B: Q's quad in P-frame, clip box (hw1,hh1); track D for the
    // frame-translation correction.
    float Dx = 0.0f, Dy = 0.0f;
    float SB = clip_quad<true>(cr * hw2, -sr * hw2, sr * hh2, cr * hh2,
                               cPx, cPy, hw1, hh1, Dx, Dy);

    // corr = cross(cQ, R_PQ * D)
    float RDx = cr * Dx - sr * Dy;
    float RDy = sr * Dx + cr * Dy;
    float corr = cQx * RDy - cQy * RDx;

    float inter = fmaxf(0.5f * (SA + SB + corr), 0.0f);
    float a1 = pw * ph;
    float a2 = qw * qh;
    float iou = inter * rcpf(a1 + a2 - inter);
    iou = fmaxf(iou, 1e-6f);
    return -__logf(iou) * w;
}

__global__ void __launch_bounds__(256, 4)
riou_loss_kernel(const float* __restrict__ pred,
                 const float* __restrict__ target,
                 const float* __restrict__ weight,
                 float* __restrict__ out,
                 int n, float inv_n)
{
    // 256 boxes/block -> 1280 floats per input array. float4-backed for
    // 16B-aligned coalesced staging stores.
    __shared__ float4 sp4[320];
    __shared__ float4 sq4[320];
    float* sp = (float*)sp4;
    float* sq = (float*)sq4;

    int nf = n * 5;
    int base_f = blockIdx.x * 1280;
    int remf = nf - base_f;              // > 0 by grid construction

    if (remf >= 1280) {
        const float4* P4 = (const float4*)(pred + base_f);
        const float4* Q4 = (const float4*)(target + base_f);
        #pragma unroll
        for (int i = threadIdx.x; i < 320; i += 256) {
            sp4[i] = P4[i];
            sq4[i] = Q4[i];
        }
    } else {
        // tail block only: scalar staging with bounds check
        for (int i = threadIdx.x; i < remf; i += 256) {
            sp[i] = pred[base_f + i];
            sq[i] = target[base_f + i];
        }
    }
    __syncthreads();

    int t = blockIdx.x * blockDim.x + threadIdx.x;
    float loss = 0.0f;
    if (t < n) {
        int j = threadIdx.x * 5;
        // lanes l and l+32 read bank (5l)%32 == (5l+160)%32 -> 2-way alias (free)
        float p0 = sp[j + 0], p1 = sp[j + 1], p2 = sp[j + 2], p3 = sp[j + 3], p4 = sp[j + 4];
        float q0 = sq[j + 0], q1 = sq[j + 1], q2 = sq[j + 2], q3 = sq[j + 3], q4 = sq[j + 4];
        float w = weight[t];             // contiguous across lanes: coalesced
        loss = riou_one(p0, p1, p2, p3, p4, q0, q1, q2, q3, q4, w);
    }

    // block reduction: wave shuffle (width 64) -> LDS -> one atomic per block
    #pragma unroll
    for (int off = 32; off > 0; off >>= 1)
        loss += __shfl_down(loss, off, 64);

    __shared__ float ssum[4];
    int wave = threadIdx.x >> 6;
    int lane = threadIdx.x & 63;
    if (lane == 0) ssum[wave] = loss;
    __syncthreads();
    if (threadIdx.x == 0) {
        float s = ssum[0] + ssum[1] + ssum[2] + ssum[3];
        atomicAdd(out, s * inv_n);
    }
}

extern "C" void kernel_launch(void* const* d_in, const int* in_sizes, int n_in,
                              void* d_out, int out_size, void* d_ws, size_t ws_size,
                              hipStream_t stream) {
    const float* pred   = (const float*)d_in[0];
    const float* target = (const float*)d_in[1];
    const float* weight = (const float*)d_in[2];
    float* out = (float*)d_out;

    int n = in_sizes[0] / 5;

    // d_out is poisoned to 0xAA before every timed launch -> zero it ourselves.
    hipMemsetAsync(out, 0, sizeof(float), stream);

    int block = 256;
    int grid = (n + block - 1) / block;
    riou_loss_kernel<<<grid, block, 0, stream>>>(pred, target, weight, out,
                                                 n, 1.0f / (float)n);
}

// Round 4
// 91.787 us; speedup vs baseline: 1.4152x; 1.4152x over previous
//
#include <hip/hip_runtime.h>
#include <math.h>

// RotatedIoULoss: per-pair rotated-box IoU loss, mean-reduced to one f32 scalar.
// Inputs: d_in[0]=pred (n,5) f32, d_in[1]=target (n,5) f32, d_in[2]=weight (n,) f32.
// Output: d_out[0] = mean(-log(max(iou,1e-6)) * weight).
//
// R1: branchless Green's-theorem intersection.
// R2: 4 boxes/thread, float4 loads, ILP.
// R3: rectangle structure — AABB slab clip per edge; ~310 VALU-equiv/box.
// R4/R5 (FAILED): occupancy theories; counters showed VALU idle (14%).
// R6 (NEUTRAL): LDS-staged coalesced loads — identical 55us to R5's
//     uncoalesced loads. Conclusion: load path never was the limiter.
// R7: the limiter consistent with ALL evidence is the single-address
//     device-scope atomicAdd: 3907 blocks x same dword across 8 XCDs
//     serialize at the home L2 (~34 cy/op effective = 132k cy = whole
//     kernel), backpressuring end-of-kernel retirement (occupancy 47%
//     with idle waves). Fix: two-stage reduction. Kernel 1 stores one
//     partial per block to d_ws (no contention); kernel 2 (1 block)
//     reduces partials and writes out directly (also kills the memset
//     dispatch since the store overwrites the poison).

__device__ __forceinline__ float rcpf(float x) { return __builtin_amdgcn_rcpf(x); }

template <bool TRACK>
__device__ __forceinline__ void clip_edge(float u0, float v0, float dx, float dy,
                                          float rx, float ry, float hw, float hh,
                                          float& S, float& Dx, float& Dy)
{
    float ta = (-hw - u0) * rx;
    float tb = ( hw - u0) * rx;
    float tc = (-hh - v0) * ry;
    float td = ( hh - v0) * ry;
    float tumin = fminf(ta, tb), tumax = fmaxf(ta, tb);
    float tvmin = fminf(tc, td), tvmax = fmaxf(tc, td);
    float t0 = fmaxf(fmaxf(tumin, tvmin), 0.0f);   // v_max3
    float t1 = fminf(fminf(tumax, tvmax), 1.0f);   // v_min3
    bool valid = t1 > t0;
    float sx = fmaf(t0, dx, u0), sy = fmaf(t0, dy, v0);
    float ex = fmaf(t1, dx, u0), ey = fmaf(t1, dy, v0);
    float c = sx * ey - sy * ex;
    S += valid ? c : 0.0f;
    if (TRACK) {
        Dx += valid ? (ex - sx) : 0.0f;
        Dy += valid ? (ey - sy) : 0.0f;
    }
}

// Quad with CCW corners (+U+V, -U+V, -U-V, +U-V) + c, clipped to AABB(hw,hh).
// Edge vectors are (-2U, -2V, +2U, +2V) -> only 4 distinct rcps.
template <bool TRACK>
__device__ __forceinline__ float clip_quad(float Ux, float Uy, float Vx, float Vy,
                                           float cx, float cy, float hw, float hh,
                                           float& Dx, float& Dy)
{
    float d0x = -2.0f * Ux, d0y = -2.0f * Uy;   // edge 0 and (negated) edge 2
    float d1x = -2.0f * Vx, d1y = -2.0f * Vy;   // edge 1 and (negated) edge 3
    float r0x = rcpf(d0x), r0y = rcpf(d0y);
    float r1x = rcpf(d1x), r1y = rcpf(d1y);

    float sxv = Ux + Vx, syv = Uy + Vy;   // c0 offset
    float dxv = Ux - Vx, dyv = Uy - Vy;   // c3 offset

    float S = 0.0f;
    clip_edge<TRACK>( sxv + cx,  syv + cy,  d0x,  d0y,  r0x,  r0y, hw, hh, S, Dx, Dy);
    clip_edge<TRACK>(-dxv + cx, -dyv + cy,  d1x,  d1y,  r1x,  r1y, hw, hh, S, Dx, Dy);
    clip_edge<TRACK>(-sxv + cx, -syv + cy, -d0x, -d0y, -r0x, -r0y, hw, hh, S, Dx, Dy);
    clip_edge<TRACK>( dxv + cx,  dyv + cy, -d1x, -d1y, -r1x, -r1y, hw, hh, S, Dx, Dy);
    return S;
}

__device__ __forceinline__ float riou_one(float px, float py, float pw, float ph, float pa,
                                          float qx, float qy, float qw, float qh, float qa,
                                          float w)
{
    float hw1 = 0.5f * pw, hh1 = 0.5f * ph;
    float hw2 = 0.5f * qw, hh2 = 0.5f * qh;

    float ca = __cosf(pa), sa = __sinf(pa);
    float delta = pa - qa;
    float cr = __cosf(delta), sr = __sinf(delta);

    float ox = qx - px, oy = qy - py;          // q - p in world frame
    // Q center in P-frame: R(-pa) * o
    float cPx =  ca * ox + sa * oy;
    float cPy = -sa * ox + ca * oy;
    // P center in Q-frame: cQ = -R_PQ * cP, R_PQ = [cr -sr; sr cr]
    float cQx = -(cr * cPx - sr * cPy);
    float cQy = -(sr * cPx + cr * cPy);

    // Set A: P's quad in Q-frame, clip box (hw2,hh2).
    float dum0 = 0.0f, dum1 = 0.0f;
    float SA = clip_quad<false>(cr * hw1, sr * hw1, -sr * hh1, cr * hh1,
                                cQx, cQy, hw2, hh2, dum0, dum1);

    // Set B: Q's quad in P-frame, clip box (hw1,hh1); track D for the
    // frame-translation correction.
    float Dx = 0.0f, Dy = 0.0f;
    float SB = clip_quad<true>(cr * hw2, -sr * hw2, sr * hh2, cr * hh2,
                               cPx, cPy, hw1, hh1, Dx, Dy);

    // corr = cross(cQ, R_PQ * D)
    float RDx = cr * Dx - sr * Dy;
    float RDy = sr * Dx + cr * Dy;
    float corr = cQx * RDy - cQy * RDx;

    float inter = fmaxf(0.5f * (SA + SB + corr), 0.0f);
    float a1 = pw * ph;
    float a2 = qw * qh;
    float iou = inter * rcpf(a1 + a2 - inter);
    iou = fmaxf(iou, 1e-6f);
    return -__logf(iou) * w;
}

__global__ void __launch_bounds__(256)
riou_loss_kernel(const float* __restrict__ pred,
                 const float* __restrict__ target,
                 const float* __restrict__ weight,
                 float* __restrict__ partial,
                 int n)
{
    // 256 boxes/block -> 1280 floats per input array. float4-backed for
    // 16B-aligned coalesced staging stores.
    __shared__ float4 sp4[320];
    __shared__ float4 sq4[320];
    float* sp = (float*)sp4;
    float* sq = (float*)sq4;

    int nf = n * 5;
    int base_f = blockIdx.x * 1280;
    int remf = nf - base_f;              // > 0 by grid construction

    if (remf >= 1280) {
        const float4* P4 = (const float4*)(pred + base_f);
        const float4* Q4 = (const float4*)(target + base_f);
        #pragma unroll
        for (int i = threadIdx.x; i < 320; i += 256) {
            sp4[i] = P4[i];
            sq4[i] = Q4[i];
        }
    } else {
        // tail block only: scalar staging with bounds check
        for (int i = threadIdx.x; i < remf; i += 256) {
            sp[i] = pred[base_f + i];
            sq[i] = target[base_f + i];
        }
    }
    __syncthreads();

    int t = blockIdx.x * blockDim.x + threadIdx.x;
    float loss = 0.0f;
    if (t < n) {
        int j = threadIdx.x * 5;
        // lanes l and l+32 read bank (5l)%32 == (5l+160)%32 -> 2-way alias (free)
        float p0 = sp[j + 0], p1 = sp[j + 1], p2 = sp[j + 2], p3 = sp[j + 3], p4 = sp[j + 4];
        float q0 = sq[j + 0], q1 = sq[j + 1], q2 = sq[j + 2], q3 = sq[j + 3], q4 = sq[j + 4];
        float w = weight[t];             // contiguous across lanes: coalesced
        loss = riou_one(p0, p1, p2, p3, p4, q0, q1, q2, q3, q4, w);
    }

    // block reduction: wave shuffle (width 64) -> LDS -> one store per block
    #pragma unroll
    for (int off = 32; off > 0; off >>= 1)
        loss += __shfl_down(loss, off, 64);

    __shared__ float ssum[4];
    int wave = threadIdx.x >> 6;
    int lane = threadIdx.x & 63;
    if (lane == 0) ssum[wave] = loss;
    __syncthreads();
    if (threadIdx.x == 0) {
        // contention-free: one plain store per block
        partial[blockIdx.x] = ssum[0] + ssum[1] + ssum[2] + ssum[3];
    }
}

__global__ void __launch_bounds__(256)
reduce_partials_kernel(const float* __restrict__ partial, float* __restrict__ out,
                       int num, float inv_n)
{
    float s = 0.0f;
    for (int i = threadIdx.x; i < num; i += 256)
        s += partial[i];

    #pragma unroll
    for (int off = 32; off > 0; off >>= 1)
        s += __shfl_down(s, off, 64);

    __shared__ float ssum[4];
    int wave = threadIdx.x >> 6;
    int lane = threadIdx.x & 63;
    if (lane == 0) ssum[wave] = s;
    __syncthreads();
    if (threadIdx.x == 0) {
        // plain store overwrites the 0xAA poison -> no memset dispatch needed
        out[0] = (ssum[0] + ssum[1] + ssum[2] + ssum[3]) * inv_n;
    }
}

extern "C" void kernel_launch(void* const* d_in, const int* in_sizes, int n_in,
                              void* d_out, int out_size, void* d_ws, size_t ws_size,
                              hipStream_t stream) {
    const float* pred   = (const float*)d_in[0];
    const float* target = (const float*)d_in[1];
    const float* weight = (const float*)d_in[2];
    float* out = (float*)d_out;
    float* partial = (float*)d_ws;

    int n = in_sizes[0] / 5;

    int block = 256;
    int grid = (n + block - 1) / block;

    riou_loss_kernel<<<grid, block, 0, stream>>>(pred, target, weight, partial, n);
    reduce_partials_kernel<<<1, block, 0, stream>>>(partial, out, grid,
                                                    1.0f / (float)n);
}

// Round 5
// 90.833 us; speedup vs baseline: 1.4301x; 1.0105x over previous
//
#include <hip/hip_runtime.h>
#include <math.h>

// RotatedIoULoss: per-pair rotated-box IoU loss, mean-reduced to one f32 scalar.
// Inputs: d_in[0]=pred (n,5) f32, d_in[1]=target (n,5) f32, d_in[2]=weight (n,) f32.
// Output: d_out[0] = mean(-log(max(iou,1e-6)) * weight).
//
// R1: branchless Green's-theorem intersection.
// R2: 4 boxes/thread, float4 loads, ILP.
// R3: rectangle structure — AABB slab clip per edge; ~310 VALU-equiv/box.
// R4/R5 (FAILED): occupancy theories — later shown to be atomic-bound era.
// R6 (NEUTRAL): LDS-staged coalesced loads; load path wasn't the limiter.
// R7 (WIN −38us): two-stage reduction removed the single-address device
//     atomicAdd (3907 blocks serializing at one L2 line). riou kernel now
//     ~15-16us, reduce ~4us.
// R8: close the gap to the ~9us floor — 2 boxes/thread with dual
//     independent pipelines (ILP-2) on the staged structure. 512 boxes /
//     block (LDS 20.5KiB -> 7 blocks/CU), grid 1954: per-block serial
//     chain (stage -> barrier -> ds_read -> ~700cy dependent clip math)
//     now overlaps two boxes in-thread; staging/barrier/store amortized
//     2x; partial count halved for kernel 2.

__device__ __forceinline__ float rcpf(float x) { return __builtin_amdgcn_rcpf(x); }

template <bool TRACK>
__device__ __forceinline__ void clip_edge(float u0, float v0, float dx, float dy,
                                          float rx, float ry, float hw, float hh,
                                          float& S, float& Dx, float& Dy)
{
    float ta = (-hw - u0) * rx;
    float tb = ( hw - u0) * rx;
    float tc = (-hh - v0) * ry;
    float td = ( hh - v0) * ry;
    float tumin = fminf(ta, tb), tumax = fmaxf(ta, tb);
    float tvmin = fminf(tc, td), tvmax = fmaxf(tc, td);
    float t0 = fmaxf(fmaxf(tumin, tvmin), 0.0f);   // v_max3
    float t1 = fminf(fminf(tumax, tvmax), 1.0f);   // v_min3
    bool valid = t1 > t0;
    float sx = fmaf(t0, dx, u0), sy = fmaf(t0, dy, v0);
    float ex = fmaf(t1, dx, u0), ey = fmaf(t1, dy, v0);
    float c = sx * ey - sy * ex;
    S += valid ? c : 0.0f;
    if (TRACK) {
        Dx += valid ? (ex - sx) : 0.0f;
        Dy += valid ? (ey - sy) : 0.0f;
    }
}

// Quad with CCW corners (+U+V, -U+V, -U-V, +U-V) + c, clipped to AABB(hw,hh).
template <bool TRACK>
__device__ __forceinline__ float clip_quad(float Ux, float Uy, float Vx, float Vy,
                                           float cx, float cy, float hw, float hh,
                                           float& Dx, float& Dy)
{
    float d0x = -2.0f * Ux, d0y = -2.0f * Uy;
    float d1x = -2.0f * Vx, d1y = -2.0f * Vy;
    float r0x = rcpf(d0x), r0y = rcpf(d0y);
    float r1x = rcpf(d1x), r1y = rcpf(d1y);

    float sxv = Ux + Vx, syv = Uy + Vy;
    float dxv = Ux - Vx, dyv = Uy - Vy;

    float S = 0.0f;
    clip_edge<TRACK>( sxv + cx,  syv + cy,  d0x,  d0y,  r0x,  r0y, hw, hh, S, Dx, Dy);
    clip_edge<TRACK>(-dxv + cx, -dyv + cy,  d1x,  d1y,  r1x,  r1y, hw, hh, S, Dx, Dy);
    clip_edge<TRACK>(-sxv + cx, -syv + cy, -d0x, -d0y, -r0x, -r0y, hw, hh, S, Dx, Dy);
    clip_edge<TRACK>( dxv + cx,  dyv + cy, -d1x, -d1y, -r1x, -r1y, hw, hh, S, Dx, Dy);
    return S;
}

__device__ __forceinline__ float riou_one(float px, float py, float pw, float ph, float pa,
                                          float qx, float qy, float qw, float qh, float qa,
                                          float w)
{
    float hw1 = 0.5f * pw, hh1 = 0.5f * ph;
    float hw2 = 0.5f * qw, hh2 = 0.5f * qh;

    float ca = __cosf(pa), sa = __sinf(pa);
    float delta = pa - qa;
    float cr = __cosf(delta), sr = __sinf(delta);

    float ox = qx - px, oy = qy - py;
    float cPx =  ca * ox + sa * oy;
    float cPy = -sa * ox + ca * oy;
    float cQx = -(cr * cPx - sr * cPy);
    float cQy = -(sr * cPx + cr * cPy);

    float dum0 = 0.0f, dum1 = 0.0f;
    float SA = clip_quad<false>(cr * hw1, sr * hw1, -sr * hh1, cr * hh1,
                                cQx, cQy, hw2, hh2, dum0, dum1);

    float Dx = 0.0f, Dy = 0.0f;
    float SB = clip_quad<true>(cr * hw2, -sr * hw2, sr * hh2, cr * hh2,
                               cPx, cPy, hw1, hh1, Dx, Dy);

    float RDx = cr * Dx - sr * Dy;
    float RDy = sr * Dx + cr * Dy;
    float corr = cQx * RDy - cQy * RDx;

    float inter = fmaxf(0.5f * (SA + SB + corr), 0.0f);
    float a1 = pw * ph;
    float a2 = qw * qh;
    float iou = inter * rcpf(a1 + a2 - inter);
    iou = fmaxf(iou, 1e-6f);
    return -__logf(iou) * w;
}

// 512 boxes/block -> 2560 floats (= 640 float4) per input array.
__global__ void __launch_bounds__(256, 4)
riou_loss_kernel(const float* __restrict__ pred,
                 const float* __restrict__ target,
                 const float* __restrict__ weight,
                 float* __restrict__ partial,
                 int n)
{
    __shared__ float4 sp4[640];
    __shared__ float4 sq4[640];
    float* sp = (float*)sp4;
    float* sq = (float*)sq4;

    int nf = n * 5;
    int base_f = blockIdx.x * 2560;
    int remf = nf - base_f;              // > 0 by grid construction

    if (remf >= 2560) {
        const float4* P4 = (const float4*)(pred + base_f);
        const float4* Q4 = (const float4*)(target + base_f);
        #pragma unroll
        for (int i = threadIdx.x; i < 640; i += 256) {
            sp4[i] = P4[i];
            sq4[i] = Q4[i];
        }
    } else {
        // tail block only: scalar staging with bounds check
        for (int i = threadIdx.x; i < remf; i += 256) {
            sp[i] = pred[base_f + i];
            sq[i] = target[base_f + i];
        }
    }
    __syncthreads();

    int base_box = blockIdx.x * 512;
    float loss = 0.0f;

    if (base_box + 512 <= n) {
        // hot path: both boxes valid — two independent pipelines, the
        // compiler interleaves them for ILP-2 on the dependent clip chains.
        int j0 = threadIdx.x * 5;
        int j1 = j0 + 1280;              // box threadIdx.x + 256
        float A0 = riou_one(sp[j0+0], sp[j0+1], sp[j0+2], sp[j0+3], sp[j0+4],
                            sq[j0+0], sq[j0+1], sq[j0+2], sq[j0+3], sq[j0+4],
                            weight[base_box + threadIdx.x]);
        float A1 = riou_one(sp[j1+0], sp[j1+1], sp[j1+2], sp[j1+3], sp[j1+4],
                            sq[j1+0], sq[j1+1], sq[j1+2], sq[j1+3], sq[j1+4],
                            weight[base_box + 256 + threadIdx.x]);
        loss = A0 + A1;
    } else {
        // tail block: per-box guards
        #pragma unroll
        for (int h = 0; h < 2; h++) {
            int local = threadIdx.x + h * 256;
            int t = base_box + local;
            if (t < n) {
                int j = local * 5;
                loss += riou_one(sp[j+0], sp[j+1], sp[j+2], sp[j+3], sp[j+4],
                                 sq[j+0], sq[j+1], sq[j+2], sq[j+3], sq[j+4],
                                 weight[t]);
            }
        }
    }

    // block reduction: wave shuffle (width 64) -> LDS -> one store per block
    #pragma unroll
    for (int off = 32; off > 0; off >>= 1)
        loss += __shfl_down(loss, off, 64);

    __shared__ float ssum[4];
    int wave = threadIdx.x >> 6;
    int lane = threadIdx.x & 63;
    if (lane == 0) ssum[wave] = loss;
    __syncthreads();
    if (threadIdx.x == 0) {
        // contention-free: one plain store per block
        partial[blockIdx.x] = ssum[0] + ssum[1] + ssum[2] + ssum[3];
    }
}

__global__ void __launch_bounds__(256)
reduce_partials_kernel(const float* __restrict__ partial, float* __restrict__ out,
                       int num, float inv_n)
{
    float s = 0.0f;
    for (int i = threadIdx.x; i < num; i += 256)
        s += partial[i];

    #pragma unroll
    for (int off = 32; off > 0; off >>= 1)
        s += __shfl_down(s, off, 64);

    __shared__ float ssum[4];
    int wave = threadIdx.x >> 6;
    int lane = threadIdx.x & 63;
    if (lane == 0) ssum[wave] = s;
    __syncthreads();
    if (threadIdx.x == 0) {
        // plain store overwrites the 0xAA poison -> no memset dispatch needed
        out[0] = (ssum[0] + ssum[1] + ssum[2] + ssum[3]) * inv_n;
    }
}

extern "C" void kernel_launch(void* const* d_in, const int* in_sizes, int n_in,
                              void* d_out, int out_size, void* d_ws, size_t ws_size,
                              hipStream_t stream) {
    const float* pred   = (const float*)d_in[0];
    const float* target = (const float*)d_in[1];
    const float* weight = (const float*)d_in[2];
    float* out = (float*)d_out;
    float* partial = (float*)d_ws;

    int n = in_sizes[0] / 5;

    int boxes_per_block = 512;
    int grid = (n + boxes_per_block - 1) / boxes_per_block;

    riou_loss_kernel<<<grid, 256, 0, stream>>>(pred, target, weight, partial, n);
    reduce_partials_kernel<<<1, 256, 0, stream>>>(partial, out, grid,
                                                  1.0f / (float)n);
}